// Round 9
// baseline (308.710 us; speedup 1.0000x reference)
//
#include <hip/hip_runtime.h>
#include <hip/hip_fp16.h>
#include <stdint.h>

typedef unsigned short u16;
typedef unsigned int u32;
typedef unsigned char u8;
typedef __attribute__((ext_vector_type(8))) short bf16x8;
typedef __attribute__((ext_vector_type(4))) short bf16x4;
typedef __attribute__((ext_vector_type(4))) float f32x4;

#define DD 128
#define CAP 64     // Poisson(16): P(deg>64) ~ 1e-20; overflow path still correct
#define STRA 136   // A/C half-tile LDS stride (u16): 272B rows, 16B-aligned
#define PSC 256.f  // perb int8 scale: q = rint(perb*256), |err| <= 0.002
#define IPSC (1.f/256.f)
#define NPART 8    // k2 row partitions (XCD-affine via blockIdx&7)

__device__ __forceinline__ float bflo(u32 u){ return __uint_as_float(u<<16); }
__device__ __forceinline__ float bfhi(u32 u){ return __uint_as_float(u & 0xffff0000u); }
__device__ __forceinline__ float bf2f(u16 u){ return __uint_as_float(((u32)u)<<16); }
__device__ __forceinline__ u16 f2bf(float f){
  u32 u = __float_as_uint(f);
  return (u16)((u + 0x7fffu + ((u>>16)&1u)) >> 16);   // RNE
}

// Tg row (384B): 32 chunks of 12B; chunk hl = [4x bf16 x (8B) | 4x int8 perb (4B)]
#define FMAXP(g, vv, vqv) do { \
    ax[0] += (vv)*bflo((g).x); ax[1] += (vv)*bfhi((g).x); \
    ax[2] += (vv)*bflo((g).y); ax[3] += (vv)*bfhi((g).y); \
    int d_ = (int)(g).z; \
    ap[0] += (vqv)*(float)(signed char)(d_); \
    ap[1] += (vqv)*(float)(signed char)(d_>>8); \
    ap[2] += (vqv)*(float)(signed char)(d_>>16); \
    ap[3] += (vqv)*(float)(d_>>24); } while(0)

// kU: fused init. (a) zero control region (COMPUTE kernel, never SDMA/memset —
// graph replay ordering), (b) pre-swizzle weights into MFMA B-fragment order,
// (c) build gather table Tg (bf16 x + int8 perb, 384B/row).
__global__ __launch_bounds__(256) void kU_init(
    const float* __restrict__ x, const float* __restrict__ perb,
    const float* __restrict__ W, const float* __restrict__ Wt,
    const float* __restrict__ W1, const float* __restrict__ W2,
    u8* __restrict__ Tg, u16* __restrict__ Bswz,
    u16* __restrict__ W1swz, u16* __restrict__ W2swz,
    int* __restrict__ deg, float* __restrict__ stats,
    float* __restrict__ gbuf, int N)
{
  int f = blockIdx.x*256 + threadIdx.x;
  if (f < N) deg[f] = 0;
  if (f < 512) stats[f] = 0.f;
  if (f < 64) gbuf[f] = 0.f;   // covers gloss + ovfc (256B block)
  if (f < 65536) {
    int idx = f;
    if (idx < 32768) {
      int j = idx & 7, lane = (idx>>3)&63, nt = (idx>>9)&15, kt = idx>>13;
      int k = kt*32 + (lane>>4)*8 + j, n = nt*16 + (lane&15);
      float v = (n < DD) ? W[k*DD + n] : Wt[k*DD + (n-DD)];
      Bswz[idx] = f2bf(v);
    } else {
      int t = idx - 32768;
      int which = t >> 14; t &= 16383;
      int j = t & 7, lane = (t>>3)&63, nt = (t>>9)&7, kt = (t>>12)&3;
      int k = kt*32 + (lane>>4)*8 + j, n = nt*16 + (lane&15);
      const float* __restrict__ src = which ? W2 : W1;
      u16* __restrict__ dst = which ? W2swz : W1swz;
      dst[t] = f2bf(src[k*DD + n]);
    }
  }
  if (f < N*32) {
    int r = f >> 5, hl = f & 31;
    float4 xa = *(const float4*)(x    + (size_t)r*DD + hl*4);
    float4 pa = *(const float4*)(perb + (size_t)r*DD + hl*4);
    u32 d0 = (u32)f2bf(xa.x) | ((u32)f2bf(xa.y) << 16);
    u32 d1 = (u32)f2bf(xa.z) | ((u32)f2bf(xa.w) << 16);
    int q0 = (int)rintf(pa.x*PSC); q0 = q0 < -127 ? -127 : (q0 > 127 ? 127 : q0);
    int q1 = (int)rintf(pa.y*PSC); q1 = q1 < -127 ? -127 : (q1 > 127 ? 127 : q1);
    int q2 = (int)rintf(pa.z*PSC); q2 = q2 < -127 ? -127 : (q2 > 127 ? 127 : q2);
    int q3 = (int)rintf(pa.w*PSC); q3 = q3 < -127 ? -127 : (q3 > 127 ? 127 : q3);
    u32 d2 = (u32)(q0 & 0xff) | ((u32)(q1 & 0xff) << 8)
           | ((u32)(q2 & 0xff) << 16) | ((u32)(q3 & 0xff) << 24);
    uint3 o; o.x = d0; o.y = d1; o.z = d2;
    *(uint3*)(Tg + (size_t)r*384 + hl*12) = o;
  }
}

// K2 (partitioned binning): part = blockIdx&7 — XCD-affine under round-robin
// dispatch; partition's perm slice stays in one L2 so 4B scatters merge.
__global__ __launch_bounds__(256) void k2_bucket(
    const int* __restrict__ row, const int* __restrict__ col,
    const float* __restrict__ val, int E, int* __restrict__ deg,
    u32* __restrict__ perm, int* __restrict__ ovfc, int* __restrict__ ovf,
    int rowsPerPart)
{
  const int part = blockIdx.x & (NPART-1);
  const int chunk = blockIdx.x >> 3;
  const int nchunk = gridDim.x >> 3;
  const int lo = part * rowsPerPart;
  const int hi = lo + rowsPerPart;
  int per = (E + nchunk - 1) / nchunk;
  int e0 = chunk * per;
  int e1 = e0 + per; if (e1 > E) e1 = E;
  for (int e = e0 + threadIdx.x; e < e1; e += 256) {
    int r = row[e];
    if (r < lo || r >= hi) continue;
    int slot = atomicAdd(&deg[r], 1);
    if (slot < CAP) {
      u32 pk = (u32)(col[e] & 0xffff)
             | ((u32)__half_as_ushort(__float2half(val[e])) << 16);
      perm[(size_t)r*CAP + slot] = pk;
    }
    else { int oi = atomicAdd(ovfc, 1); if (oi < 4096) ovf[oi] = e; }
  }
}

// K3: one wave per row; 384B/edge gathers (12B/lane dwordx3), two wave-halves
// process even/odd edges. Random-gather memory-pattern bound.
__global__ __launch_bounds__(256) void k3_spmm(
    const u32* __restrict__ perm, const int* __restrict__ deg,
    const u8* __restrict__ Tg, u16* __restrict__ T2, int N)
{
  int row = blockIdx.x*4 + (threadIdx.x >> 6);
  int l = threadIdx.x & 63;
  if (row >= N) return;
  int dg = deg[row];
  dg = dg < 0 ? 0 : (dg > CAP ? CAP : dg);       // defensive clamp
  const int half = l >> 5, hl = l & 31;
  const int loff = hl * 12;                       // byte offset in 384B row
  float ax[4] = {0.f,0.f,0.f,0.f};
  float ap[4] = {0.f,0.f,0.f,0.f};
  for (int base = 0; base < dg; base += 64) {
    u32 pk = 0;                                   // pad: c=0, v=0 (harmless gather)
    if (base + l < dg) pk = perm[(size_t)row*CAP + base + l];
    int mm = dg - base; if (mm > 64) mm = 64;
    int kmax = (mm + 1) & ~1;                     // round up to even (pad v=0)
    int j = 0;
    for (; j + 8 <= kmax; j += 8) {
      u32 p0 = (u32)__shfl((int)pk, j + half);
      u32 p1 = (u32)__shfl((int)pk, j + 2 + half);
      u32 p2 = (u32)__shfl((int)pk, j + 4 + half);
      u32 p3 = (u32)__shfl((int)pk, j + 6 + half);
      int c0 = p0 & 0xffff; c0 = (c0 < N) ? c0 : 0;
      int c1 = p1 & 0xffff; c1 = (c1 < N) ? c1 : 0;
      int c2 = p2 & 0xffff; c2 = (c2 < N) ? c2 : 0;
      int c3 = p3 & 0xffff; c3 = (c3 < N) ? c3 : 0;
      float v0 = __half2float(__ushort_as_half((u16)(p0 >> 16)));
      float v1 = __half2float(__ushort_as_half((u16)(p1 >> 16)));
      float v2 = __half2float(__ushort_as_half((u16)(p2 >> 16)));
      float v3 = __half2float(__ushort_as_half((u16)(p3 >> 16)));
      uint3 g0 = *(const uint3*)(Tg + (size_t)c0*384 + loff);
      uint3 g1 = *(const uint3*)(Tg + (size_t)c1*384 + loff);
      uint3 g2 = *(const uint3*)(Tg + (size_t)c2*384 + loff);
      uint3 g3 = *(const uint3*)(Tg + (size_t)c3*384 + loff);
      float vq0 = v0*IPSC, vq1 = v1*IPSC, vq2 = v2*IPSC, vq3 = v3*IPSC;
      FMAXP(g0, v0, vq0); FMAXP(g1, v1, vq1);
      FMAXP(g2, v2, vq2); FMAXP(g3, v3, vq3);
    }
    for (; j < kmax; j += 2) {
      u32 p0 = (u32)__shfl((int)pk, j + half);
      int c0 = p0 & 0xffff; c0 = (c0 < N) ? c0 : 0;
      float v0 = __half2float(__ushort_as_half((u16)(p0 >> 16)));
      uint3 g0 = *(const uint3*)(Tg + (size_t)c0*384 + loff);
      float vq0 = v0*IPSC;
      FMAXP(g0, v0, vq0);
    }
  }
  // combine even/odd-edge partials across halves
  #pragma unroll
  for (int i = 0; i < 4; ++i) {
    ax[i] += __shfl_xor(ax[i], 32);
    ap[i] += __shfl_xor(ap[i], 32);
  }
  // T2 row = [aggx1 (128) | aggx2=aggx1+aggp (128)]; half0 writes x1, half1 x2.
  bf16x4 ob;
  #pragma unroll
  for (int i = 0; i < 4; ++i) {
    float o = half ? (ax[i] + ap[i]) : ax[i];
    ob[i] = (short)f2bf(o);
  }
  *(bf16x4*)(T2 + (size_t)row*256 + half*128 + hl*4) = ob;  // 64 lanes x 8B
}

// K3b: overflow fallback (expected empty) — serial RMW on T2 (raw edges).
__global__ __launch_bounds__(256) void k3b_ovf(
    const int* __restrict__ rowI, const int* __restrict__ colI,
    const float* __restrict__ val, const int* __restrict__ ovfc,
    const int* __restrict__ ovf, const u8* __restrict__ Tg,
    u16* __restrict__ T2)
{
  int n = *ovfc; if (n > 4096) n = 4096;
  for (int i = 0; i < n; ++i) {
    int e = ovf[i];
    int r = rowI[e], c = colI[e];
    float v = val[e];
    int d = threadIdx.x;           // 256 threads cover the 256-wide row
    int dl = d & 127;
    const u8* tgc = Tg + (size_t)c*384 + (dl>>2)*12;
    float xv = bf2f(*(const u16*)(tgc + (dl&3)*2));
    float add = v * xv;
    if (d >= 128) {
      int qb = (int)(signed char)tgc[8 + (dl&3)];
      add = v * (xv + (float)qb * IPSC);
    }
    u16* p = &T2[(size_t)r*256 + d];
    *p = f2bf(bf2f(*p) + add);
  }
}

// K4 (R9 barrier-collapse): wave-per-column-slice; each lane's acc holds final
// (row,col) values, so AGGb / Px / Py / BN-partials store DIRECTLY from
// registers (16 lanes x 2B = 32B segments, L2 write-combines; stores are
// fire-and-forget). Only 2 __syncthreads (was 6):
//   load A -> sync -> passA MFMA -> AGGb reg-store -> passB MFMA -> Ct(LDS)
//   -> sync -> {embed from Ct, stage2 MFMA from Ct} -> partial+P reg-stores.
// Numerics bit-identical to R8.
__global__ __launch_bounds__(256, 4) void k4_gemm(
    const u16* __restrict__ T2, const u16* __restrict__ Bswz,
    const u16* __restrict__ W1swz,
    const float* __restrict__ b, const float* __restrict__ bt,
    const float* __restrict__ b1, const u8* __restrict__ Tg,
    u16* __restrict__ AGGb, float* __restrict__ outE,
    u16* __restrict__ Px, u16* __restrict__ Py,
    float* __restrict__ partial, int N, int NB)
{
  __shared__ __align__(16) u16 As1[64*STRA];   // 17408B
  __shared__ __align__(16) u16 Ct[64*STRA];    // 17408B passB C-tile (bf16)
  const int tid = threadIdx.x;
  const int r0 = blockIdx.x * 32;
  // ---- load A (64 rows: 0-31 = aggx1, 32-63 = aggx2) ----
  #pragma unroll
  for (int i = 0; i < 4; ++i) {
    int f = tid + 256*i;            // 1024 chunks: 64 A-rows x 16 chunks of 8
    int row = f >> 4, c8 = f & 15;
    int r = r0 + (row & 31);
    bf16x8 ch = {0,0,0,0,0,0,0,0};
    if (r < N) ch = *(const bf16x8*)(T2 + (size_t)r*256 + (row>>5)*128 + c8*8);
    *(bf16x8*)&As1[row*STRA + c8*8] = ch;
  }
  __syncthreads();                                        // (1)
  const int w = tid >> 6, l = tid & 63;
  const int m = l & 15, q = l >> 4;
  const int cbase = w*32 + m;        // this wave's column base (+ntl*16)
  f32x4 acc[4][2];
  bf16x8 bfrag[2][4];
  // ---- stage1 pass A: global cols 128..255 ([s1|s3]) ----
  #pragma unroll
  for (int ntl = 0; ntl < 2; ++ntl)
    #pragma unroll
    for (int kt = 0; kt < 4; ++kt)
      bfrag[ntl][kt] = *(const bf16x8*)(Bswz + ((size_t)(kt*16 + 8 + w*2 + ntl)*64 + l)*8);
  #pragma unroll
  for (int rt = 0; rt < 4; ++rt) {
    acc[rt][0] = (f32x4){0.f,0.f,0.f,0.f};
    acc[rt][1] = (f32x4){0.f,0.f,0.f,0.f};
  }
  #pragma unroll
  for (int kt = 0; kt < 4; ++kt)
    #pragma unroll
    for (int rt = 0; rt < 4; ++rt) {
      bf16x8 af = *(const bf16x8*)&As1[(rt*16 + m)*STRA + kt*32 + q*8];
      acc[rt][0] = __builtin_amdgcn_mfma_f32_16x16x32_bf16(af, bfrag[0][kt], acc[rt][0], 0, 0, 0);
      acc[rt][1] = __builtin_amdgcn_mfma_f32_16x16x32_bf16(af, bfrag[1][kt], acc[rt][1], 0, 0, 0);
    }
  // ---- AGGb [s1|s3] direct reg-store (rows<32 -> @0, rows>=32 -> @128) ----
  #pragma unroll
  for (int ntl = 0; ntl < 2; ++ntl) {
    float bv = bt[cbase + ntl*16];
    #pragma unroll
    for (int rt = 0; rt < 4; ++rt)
      #pragma unroll
      for (int i = 0; i < 4; ++i) {
        int ar = rt*16 + q*4 + i;
        int src = r0 + (ar & 31);
        if (src < N)
          AGGb[(size_t)src*256 + (ar>>5)*128 + cbase + ntl*16] = f2bf(acc[rt][ntl][i] + bv);
      }
  }
  // ---- stage1 pass B: global cols 0..127 ([s0|s2] + bias) -> Ct ----
  #pragma unroll
  for (int ntl = 0; ntl < 2; ++ntl)
    #pragma unroll
    for (int kt = 0; kt < 4; ++kt)
      bfrag[ntl][kt] = *(const bf16x8*)(Bswz + ((size_t)(kt*16 + w*2 + ntl)*64 + l)*8);
  #pragma unroll
  for (int rt = 0; rt < 4; ++rt) {
    acc[rt][0] = (f32x4){0.f,0.f,0.f,0.f};
    acc[rt][1] = (f32x4){0.f,0.f,0.f,0.f};
  }
  #pragma unroll
  for (int kt = 0; kt < 4; ++kt)
    #pragma unroll
    for (int rt = 0; rt < 4; ++rt) {
      bf16x8 af = *(const bf16x8*)&As1[(rt*16 + m)*STRA + kt*32 + q*8];
      acc[rt][0] = __builtin_amdgcn_mfma_f32_16x16x32_bf16(af, bfrag[0][kt], acc[rt][0], 0, 0, 0);
      acc[rt][1] = __builtin_amdgcn_mfma_f32_16x16x32_bf16(af, bfrag[1][kt], acc[rt][1], 0, 0, 0);
    }
  #pragma unroll
  for (int ntl = 0; ntl < 2; ++ntl) {
    float bv = b[cbase + ntl*16];
    #pragma unroll
    for (int rt = 0; rt < 4; ++rt)
      #pragma unroll
      for (int i = 0; i < 4; ++i)
        Ct[(rt*16 + q*4 + i)*STRA + cbase + ntl*16] = f2bf(acc[rt][ntl][i] + bv);
  }
  __syncthreads();                                        // (2)
  // ---- embed = x + perb + s2 (Ct rows 32-63, bias incl.); x,perb from Tg ----
  #pragma unroll
  for (int i = 0; i < 2; ++i) {
    int f = tid + 256*i;            // 512 chunks: 32 rows x 16 chunks of 8
    int rr = f >> 4, c8 = f & 15;
    int src = r0 + rr;
    if (src < N) {
      const u16* cp = &Ct[(32+rr)*STRA + c8*8];
      const u8* tg = Tg + (size_t)src*384 + c8*24;   // two 12B chunks
      uint3 ga = *(const uint3*)tg;
      uint3 gb = *(const uint3*)(tg + 12);
      int da = (int)ga.z, db = (int)gb.z;
      float4 e0, e1;
      e0.x = bflo(ga.x) + IPSC*(float)(signed char)(da)     + bf2f(cp[0]);
      e0.y = bfhi(ga.x) + IPSC*(float)(signed char)(da>>8)  + bf2f(cp[1]);
      e0.z = bflo(ga.y) + IPSC*(float)(signed char)(da>>16) + bf2f(cp[2]);
      e0.w = bfhi(ga.y) + IPSC*(float)(da>>24)              + bf2f(cp[3]);
      e1.x = bflo(gb.x) + IPSC*(float)(signed char)(db)     + bf2f(cp[4]);
      e1.y = bfhi(gb.x) + IPSC*(float)(signed char)(db>>8)  + bf2f(cp[5]);
      e1.z = bflo(gb.y) + IPSC*(float)(signed char)(db>>16) + bf2f(cp[6]);
      e1.w = bfhi(gb.y) + IPSC*(float)(db>>24)              + bf2f(cp[7]);
      float* er = outE + (size_t)src*DD + c8*8;
      *(float4*)er = e0;
      *(float4*)(er+4) = e1;
    }
  }
  // ---- stage2 MFMA: P = Ct[:, 0:128] @ W1 (A in-place, stride STRA) ----
  #pragma unroll
  for (int ntl = 0; ntl < 2; ++ntl)
    #pragma unroll
    for (int kt = 0; kt < 4; ++kt)
      bfrag[ntl][kt] = *(const bf16x8*)(W1swz + ((size_t)(kt*8 + w*2 + ntl)*64 + l)*8);
  #pragma unroll
  for (int rt = 0; rt < 4; ++rt) {
    acc[rt][0] = (f32x4){0.f,0.f,0.f,0.f};
    acc[rt][1] = (f32x4){0.f,0.f,0.f,0.f};
  }
  #pragma unroll
  for (int kt = 0; kt < 4; ++kt)
    #pragma unroll
    for (int rt = 0; rt < 4; ++rt) {
      bf16x8 af = *(const bf16x8*)&Ct[(rt*16 + m)*STRA + kt*32 + q*8];
      acc[rt][0] = __builtin_amdgcn_mfma_f32_16x16x32_bf16(af, bfrag[0][kt], acc[rt][0], 0, 0, 0);
      acc[rt][1] = __builtin_amdgcn_mfma_f32_16x16x32_bf16(af, bfrag[1][kt], acc[rt][1], 0, 0, 0);
    }
  // ---- b1 + validity + BN partials + P, all direct from registers ----
  const int bid = blockIdx.x;
  #pragma unroll
  for (int ntl = 0; ntl < 2; ++ntl) {
    float bv = b1[cbase + ntl*16];
    float s0 = 0.f, s1 = 0.f, q0 = 0.f, q1 = 0.f;
    #pragma unroll
    for (int rt = 0; rt < 4; ++rt)
      #pragma unroll
      for (int i = 0; i < 4; ++i) {
        int ar = rt*16 + q*4 + i;
        int src = r0 + (ar & 31);
        float v = (src < N) ? (acc[rt][ntl][i] + bv) : 0.f;
        if (rt < 2) { s0 += v; q0 += v*v; } else { s1 += v; q1 += v*v; }
        if (src < N)
          ((ar >> 5) ? Py : Px)[(size_t)src*DD + cbase + ntl*16] = f2bf(v);
      }
    s0 += __shfl_xor(s0, 16); s0 += __shfl_xor(s0, 32);
    s1 += __shfl_xor(s1, 16); s1 += __shfl_xor(s1, 32);
    q0 += __shfl_xor(q0, 16); q0 += __shfl_xor(q0, 32);
    q1 += __shfl_xor(q1, 16); q1 += __shfl_xor(q1, 32);
    if (l < 16) {
      int c = w*32 + l + ntl*16;
      partial[((size_t)0*NB + bid)*256 +       c] = s0;
      partial[((size_t)0*NB + bid)*256 + 128 + c] = q0;
      partial[((size_t)1*NB + bid)*256 +       c] = s1;
      partial[((size_t)1*NB + bid)*256 + 128 + c] = q1;
    }
  }
}

// K5b: reduce per-block partials into stats (few atomics).
__global__ __launch_bounds__(256) void k5b_stats(
    const float* __restrict__ partial, float* __restrict__ stats, int nb)
{
  int seg = blockIdx.y, chunk = blockIdx.x, t = threadIdx.x;
  int per = (nb + gridDim.x - 1) / gridDim.x;
  int lo = chunk*per, hi = lo+per; if (hi > nb) hi = nb;
  float s = 0.f;
  const float* p = partial + (size_t)seg*nb*256;
  for (int i = lo; i < hi; ++i) s += p[(size_t)i*256 + t];
  atomicAdd(&stats[seg*256 + t], s);
}

// K6 (R9 barrier-collapse): BN+PReLU -> MFMA (B hoisted) -> per-wave
// IN-REGISTER cosine partials (each wave holds 32 cols of every row; reduce
// over 16 m-lanes via shfl) -> 3KB cross-wave LDS combine -> 1 atomic/block.
// Cs f32 roundtrip removed: LDS 34.8 -> 21.5KB (7 blocks/CU), 3 barriers.
__global__ __launch_bounds__(256) void k6_gemm_loss(
    const u16* __restrict__ Px, const u16* __restrict__ Py,
    const u16* __restrict__ AGGb, const float* __restrict__ stats,
    const float* __restrict__ gamma, const float* __restrict__ beta,
    const float* __restrict__ aP, const u16* __restrict__ W2swz,
    const float* __restrict__ b2, float* __restrict__ gloss, int N)
{
  __shared__ __align__(16) u16 As[64*STRA];      // 17408B
  __shared__ float s1s[128], s2s[128];
  __shared__ float redp[4][64], redt[4][64], redx[4][64];   // 3KB
  const int tid = threadIdx.x;
  const int seg = blockIdx.y;
  const u16* __restrict__ P = seg ? Py : Px;
  const int toff = seg ? 0 : 128;
  const float invN = 1.f / (float)N;
  if (tid < 128) {
    float mu = stats[seg*256 + tid] * invN;
    float var = stats[seg*256 + 128 + tid] * invN - mu*mu;
    float rstd = rsqrtf(var + 1e-5f);
    float s1 = rstd * gamma[tid];
    s1s[tid] = s1;
    s2s[tid] = beta[tid] - mu*s1;
  }
  const float alpha = aP[0];
  const int r0 = blockIdx.x * 64;
  __syncthreads();                                        // (a)
  #pragma unroll
  for (int i = 0; i < 4; ++i) {
    int f = tid + 256*i;
    int row = f >> 4, c8 = f & 15;
    int r = r0 + row;
    bf16x8 ch = {0,0,0,0,0,0,0,0};
    if (r < N) ch = *(const bf16x8*)(P + (size_t)r*DD + c8*8);
    bf16x8 a;
    #pragma unroll
    for (int t2 = 0; t2 < 8; ++t2) {
      int colc = c8*8 + t2;
      float hv = bf2f((u16)ch[t2]);
      float hn = hv*s1s[colc] + s2s[colc];
      hn = hn >= 0.f ? hn : alpha*hn;
      a[t2] = (short)f2bf(hn);
    }
    *(bf16x8*)&As[row*STRA + c8*8] = a;
  }
  __syncthreads();                                        // (b)
  const int w = tid >> 6, l = tid & 63;
  const int m = l & 15, q = l >> 4;
  const int cbase = w*32 + m;
  f32x4 acc[4][2];
  bf16x8 bfrag[2][4];
  #pragma unroll
  for (int ntl = 0; ntl < 2; ++ntl)
    #pragma unroll
    for (int kt = 0; kt < 4; ++kt)
      bfrag[ntl][kt] = *(const bf16x8*)(W2swz + ((size_t)(kt*8 + w*2 + ntl)*64 + l)*8);
  #pragma unroll
  for (int rt = 0; rt < 4; ++rt) {
    acc[rt][0] = (f32x4){0.f,0.f,0.f,0.f};
    acc[rt][1] = (f32x4){0.f,0.f,0.f,0.f};
  }
  #pragma unroll
  for (int kt = 0; kt < 4; ++kt)
    #pragma unroll
    for (int rt = 0; rt < 4; ++rt) {
      bf16x8 af = *(const bf16x8*)&As[(rt*16 + m)*STRA + kt*32 + q*8];
      acc[rt][0] = __builtin_amdgcn_mfma_f32_16x16x32_bf16(af, bfrag[0][kt], acc[rt][0], 0, 0, 0);
      acc[rt][1] = __builtin_amdgcn_mfma_f32_16x16x32_bf16(af, bfrag[1][kt], acc[rt][1], 0, 0, 0);
    }
  // ---- per-wave cosine partials over this wave's 32 cols ----
  const float b20 = b2[cbase], b21 = b2[cbase + 16];
  #pragma unroll
  for (int rt = 0; rt < 4; ++rt)
    #pragma unroll
    for (int i = 0; i < 4; ++i) {
      int row = rt*16 + q*4 + i;
      int r = r0 + row;
      float p0 = 0.f, p1 = 0.f, t0 = 0.f, t1 = 0.f;
      if (r < N) {
        p0 = acc[rt][0][i] + b20;
        p1 = acc[rt][1][i] + b21;
        t0 = bf2f(AGGb[(size_t)r*256 + toff + cbase]);
        t1 = bf2f(AGGb[(size_t)r*256 + toff + cbase + 16]);
      }
      float pp = p0*p0 + p1*p1;
      float tt = t0*t0 + t1*t1;
      float pt = p0*t0 + p1*t1;
      pp += __shfl_xor(pp, 1); pp += __shfl_xor(pp, 2);
      pp += __shfl_xor(pp, 4); pp += __shfl_xor(pp, 8);
      tt += __shfl_xor(tt, 1); tt += __shfl_xor(tt, 2);
      tt += __shfl_xor(tt, 4); tt += __shfl_xor(tt, 8);
      pt += __shfl_xor(pt, 1); pt += __shfl_xor(pt, 2);
      pt += __shfl_xor(pt, 4); pt += __shfl_xor(pt, 8);
      if (m == 0) { redp[w][row] = pp; redt[w][row] = tt; redx[w][row] = pt; }
    }
  __syncthreads();                                        // (c)
  if (tid < 64) {
    int r = r0 + tid;
    float pp = redp[0][tid] + redp[1][tid] + redp[2][tid] + redp[3][tid];
    float tt = redt[0][tid] + redt[1][tid] + redt[2][tid] + redt[3][tid];
    float pt = redx[0][tid] + redx[1][tid] + redx[2][tid] + redx[3][tid];
    float ls = 0.f;
    if (r < N) ls = 2.f - 2.f * pt * rsqrtf(pp * tt);
    ls += __shfl_xor(ls, 1);  ls += __shfl_xor(ls, 2);
    ls += __shfl_xor(ls, 4);  ls += __shfl_xor(ls, 8);
    ls += __shfl_xor(ls, 16); ls += __shfl_xor(ls, 32);
    if (tid == 0) atomicAdd(gloss, ls);
  }
}

__global__ void k7_loss(const float* __restrict__ gloss, float* __restrict__ out, int N, int total)
{
  out[total] = gloss[0] / (float)N;
}

extern "C" void kernel_launch(void* const* d_in, const int* in_sizes, int n_in,
                              void* d_out, int out_size, void* d_ws, size_t ws_size,
                              hipStream_t stream)
{
  const float* x    = (const float*)d_in[0];
  const float* perb = (const float*)d_in[1];
  const int*   erow = (const int*)d_in[2];
  const int*   ecol = (const int*)d_in[3];
  const float* eval_= (const float*)d_in[4];
  const float* W    = (const float*)d_in[5];
  const float* b    = (const float*)d_in[6];
  const float* Wt   = (const float*)d_in[7];
  const float* bt   = (const float*)d_in[8];
  const float* W1   = (const float*)d_in[9];
  const float* b1   = (const float*)d_in[10];
  const float* gam  = (const float*)d_in[11];
  const float* bet  = (const float*)d_in[12];
  const float* aP   = (const float*)d_in[13];
  const float* W2   = (const float*)d_in[14];
  const float* b2   = (const float*)d_in[15];
  const int N = in_sizes[0] / DD;
  const int E = in_sizes[2];
  const int NB4 = (N + 31)/32;
  const int NB5 = (N + 63)/64;
  const int rowsPerPart = (N + NPART - 1) / NPART;

  char* ws = (char*)d_ws;
  size_t off = 0;
  auto alloc = [&](size_t bytes) -> void* {
    void* p = ws + off;
    off += (bytes + 255) & ~(size_t)255;
    return p;
  };
  u16*   AGGb = (u16*)  alloc((size_t)N*256*sizeof(u16));   // 25.6 MB [s1|s3]
  u8*    Tg   = (u8*)   alloc((size_t)N*384);               // 19.2 MB gather table
  u16*   T2   = (u16*)  alloc((size_t)N*256*sizeof(u16));   // 25.6 MB
  u16*   Px   = (u16*)  alloc((size_t)N*DD*sizeof(u16));    // 12.8 MB
  u16*   Py   = (u16*)  alloc((size_t)N*DD*sizeof(u16));    // 12.8 MB
  int*   deg  = (int*)  alloc((size_t)N*sizeof(int));
  float* stats= (float*)alloc(512*sizeof(float));
  float* gloss= (float*)alloc(256);
  int*   ovfc = (int*)((char*)gloss + 64);
  u32*   perm = (u32*)  alloc((size_t)N*CAP*sizeof(u32));   // 12.8 MB packed
  int*   ovf  = (int*)  alloc(4096*sizeof(int));
  u16*   Bswz = (u16*)  alloc(32768*sizeof(u16));
  u16*   W1swz= (u16*)  alloc(16384*sizeof(u16));
  u16*   W2swz= (u16*)  alloc(16384*sizeof(u16));
  float* partial = (float*)alloc((size_t)2*NB4*256*sizeof(float)); // 3.2 MB
  if (ws_size < off) return;

  kU_init<<<(N*32 + 255)/256, 256, 0, stream>>>(x, perb, W, Wt, W1, W2,
                                                Tg, Bswz, W1swz, W2swz,
                                                deg, stats, gloss, N);
  k2_bucket<<<2048, 256, 0, stream>>>(erow, ecol, eval_, E, deg, perm, ovfc, ovf,
                                      rowsPerPart);
  k3_spmm<<<(N + 3)/4, 256, 0, stream>>>(perm, deg, Tg, T2, N);
  k3b_ovf<<<1, 256, 0, stream>>>(erow, ecol, eval_, ovfc, ovf, Tg, T2);
  k4_gemm<<<NB4, 256, 0, stream>>>(T2, Bswz, W1swz, b, bt, b1, Tg,
                                   AGGb, (float*)d_out, Px, Py, partial, N, NB4);
  k5b_stats<<<dim3(16, 2), 256, 0, stream>>>(partial, stats, NB4);
  k6_gemm_loss<<<dim3(NB5, 2), 256, 0, stream>>>(Px, Py, AGGb, stats, gam, bet, aP,
                                                 W2swz, b2, gloss, N);
  k7_loss<<<1, 1, 0, stream>>>(gloss, (float*)d_out, N, N*DD);
}

// Round 10
// 303.440 us; speedup vs baseline: 1.0174x; 1.0174x over previous
//
#include <hip/hip_runtime.h>
#include <hip/hip_fp16.h>
#include <stdint.h>

typedef unsigned short u16;
typedef unsigned int u32;
typedef unsigned char u8;
typedef __attribute__((ext_vector_type(8))) short bf16x8;
typedef __attribute__((ext_vector_type(4))) short bf16x4;
typedef __attribute__((ext_vector_type(4))) float f32x4;

#define DD 128
#define CAP 64     // Poisson(16): P(deg>64) ~ 1e-20; overflow path still correct
#define STRA 136   // A/C half-tile LDS stride (u16): 272B rows, 16B-aligned
#define PSC 256.f  // perb int8 scale: q = rint(perb*256), |err| <= 0.002
#define IPSC (1.f/256.f)
#define NPART 8    // k2 row partitions (XCD-affine via blockIdx&7)

__device__ __forceinline__ float bflo(u32 u){ return __uint_as_float(u<<16); }
__device__ __forceinline__ float bfhi(u32 u){ return __uint_as_float(u & 0xffff0000u); }
__device__ __forceinline__ float bf2f(u16 u){ return __uint_as_float(((u32)u)<<16); }
__device__ __forceinline__ u16 f2bf(float f){
  u32 u = __float_as_uint(f);
  return (u16)((u + 0x7fffu + ((u>>16)&1u)) >> 16);   // RNE
}

// Tg row (384B): 32 chunks of 12B; chunk hl = [4x bf16 x (8B) | 4x int8 perb (4B)]
#define FMAXP(g, vv, vqv) do { \
    ax[0] += (vv)*bflo((g).x); ax[1] += (vv)*bfhi((g).x); \
    ax[2] += (vv)*bflo((g).y); ax[3] += (vv)*bfhi((g).y); \
    int d_ = (int)(g).z; \
    ap[0] += (vqv)*(float)(signed char)(d_); \
    ap[1] += (vqv)*(float)(signed char)(d_>>8); \
    ap[2] += (vqv)*(float)(signed char)(d_>>16); \
    ap[3] += (vqv)*(float)(d_>>24); } while(0)

// kU: fused init. (a) zero control region (COMPUTE kernel, never SDMA/memset —
// graph replay ordering), (b) pre-swizzle weights into MFMA B-fragment order,
// (c) build gather table Tg (bf16 x + int8 perb, 384B/row).
__global__ __launch_bounds__(256) void kU_init(
    const float* __restrict__ x, const float* __restrict__ perb,
    const float* __restrict__ W, const float* __restrict__ Wt,
    const float* __restrict__ W1, const float* __restrict__ W2,
    u8* __restrict__ Tg, u16* __restrict__ Bswz,
    u16* __restrict__ W1swz, u16* __restrict__ W2swz,
    int* __restrict__ deg, float* __restrict__ stats,
    float* __restrict__ gbuf, int N)
{
  int f = blockIdx.x*256 + threadIdx.x;
  if (f < N) deg[f] = 0;
  if (f < 512) stats[f] = 0.f;
  if (f < 64) gbuf[f] = 0.f;   // covers gloss + ovfc (256B block)
  if (f < 65536) {
    int idx = f;
    if (idx < 32768) {
      int j = idx & 7, lane = (idx>>3)&63, nt = (idx>>9)&15, kt = idx>>13;
      int k = kt*32 + (lane>>4)*8 + j, n = nt*16 + (lane&15);
      float v = (n < DD) ? W[k*DD + n] : Wt[k*DD + (n-DD)];
      Bswz[idx] = f2bf(v);
    } else {
      int t = idx - 32768;
      int which = t >> 14; t &= 16383;
      int j = t & 7, lane = (t>>3)&63, nt = (t>>9)&7, kt = (t>>12)&3;
      int k = kt*32 + (lane>>4)*8 + j, n = nt*16 + (lane&15);
      const float* __restrict__ src = which ? W2 : W1;
      u16* __restrict__ dst = which ? W2swz : W1swz;
      dst[t] = f2bf(src[k*DD + n]);
    }
  }
  if (f < N*32) {
    int r = f >> 5, hl = f & 31;
    float4 xa = *(const float4*)(x    + (size_t)r*DD + hl*4);
    float4 pa = *(const float4*)(perb + (size_t)r*DD + hl*4);
    u32 d0 = (u32)f2bf(xa.x) | ((u32)f2bf(xa.y) << 16);
    u32 d1 = (u32)f2bf(xa.z) | ((u32)f2bf(xa.w) << 16);
    int q0 = (int)rintf(pa.x*PSC); q0 = q0 < -127 ? -127 : (q0 > 127 ? 127 : q0);
    int q1 = (int)rintf(pa.y*PSC); q1 = q1 < -127 ? -127 : (q1 > 127 ? 127 : q1);
    int q2 = (int)rintf(pa.z*PSC); q2 = q2 < -127 ? -127 : (q2 > 127 ? 127 : q2);
    int q3 = (int)rintf(pa.w*PSC); q3 = q3 < -127 ? -127 : (q3 > 127 ? 127 : q3);
    u32 d2 = (u32)(q0 & 0xff) | ((u32)(q1 & 0xff) << 8)
           | ((u32)(q2 & 0xff) << 16) | ((u32)(q3 & 0xff) << 24);
    uint3 o; o.x = d0; o.y = d1; o.z = d2;
    *(uint3*)(Tg + (size_t)r*384 + hl*12) = o;
  }
}

// K2 (partitioned binning): part = blockIdx&7 — XCD-affine under round-robin
// dispatch; partition's perm slice stays in one L2 so 4B scatters merge.
__global__ __launch_bounds__(256) void k2_bucket(
    const int* __restrict__ row, const int* __restrict__ col,
    const float* __restrict__ val, int E, int* __restrict__ deg,
    u32* __restrict__ perm, int* __restrict__ ovfc, int* __restrict__ ovf,
    int rowsPerPart)
{
  const int part = blockIdx.x & (NPART-1);
  const int chunk = blockIdx.x >> 3;
  const int nchunk = gridDim.x >> 3;
  const int lo = part * rowsPerPart;
  const int hi = lo + rowsPerPart;
  int per = (E + nchunk - 1) / nchunk;
  int e0 = chunk * per;
  int e1 = e0 + per; if (e1 > E) e1 = E;
  for (int e = e0 + threadIdx.x; e < e1; e += 256) {
    int r = row[e];
    if (r < lo || r >= hi) continue;
    int slot = atomicAdd(&deg[r], 1);
    if (slot < CAP) {
      u32 pk = (u32)(col[e] & 0xffff)
             | ((u32)__half_as_ushort(__float2half(val[e])) << 16);
      perm[(size_t)r*CAP + slot] = pk;
    }
    else { int oi = atomicAdd(ovfc, 1); if (oi < 4096) ovf[oi] = e; }
  }
}

// K3: one wave per row; 384B/edge gathers (12B/lane dwordx3), two wave-halves
// process even/odd edges. Random-gather memory-pattern bound.
__global__ __launch_bounds__(256) void k3_spmm(
    const u32* __restrict__ perm, const int* __restrict__ deg,
    const u8* __restrict__ Tg, u16* __restrict__ T2, int N)
{
  int row = blockIdx.x*4 + (threadIdx.x >> 6);
  int l = threadIdx.x & 63;
  if (row >= N) return;
  int dg = deg[row];
  dg = dg < 0 ? 0 : (dg > CAP ? CAP : dg);       // defensive clamp
  const int half = l >> 5, hl = l & 31;
  const int loff = hl * 12;                       // byte offset in 384B row
  float ax[4] = {0.f,0.f,0.f,0.f};
  float ap[4] = {0.f,0.f,0.f,0.f};
  for (int base = 0; base < dg; base += 64) {
    u32 pk = 0;                                   // pad: c=0, v=0 (harmless gather)
    if (base + l < dg) pk = perm[(size_t)row*CAP + base + l];
    int mm = dg - base; if (mm > 64) mm = 64;
    int kmax = (mm + 1) & ~1;                     // round up to even (pad v=0)
    int j = 0;
    for (; j + 8 <= kmax; j += 8) {
      u32 p0 = (u32)__shfl((int)pk, j + half);
      u32 p1 = (u32)__shfl((int)pk, j + 2 + half);
      u32 p2 = (u32)__shfl((int)pk, j + 4 + half);
      u32 p3 = (u32)__shfl((int)pk, j + 6 + half);
      int c0 = p0 & 0xffff; c0 = (c0 < N) ? c0 : 0;
      int c1 = p1 & 0xffff; c1 = (c1 < N) ? c1 : 0;
      int c2 = p2 & 0xffff; c2 = (c2 < N) ? c2 : 0;
      int c3 = p3 & 0xffff; c3 = (c3 < N) ? c3 : 0;
      float v0 = __half2float(__ushort_as_half((u16)(p0 >> 16)));
      float v1 = __half2float(__ushort_as_half((u16)(p1 >> 16)));
      float v2 = __half2float(__ushort_as_half((u16)(p2 >> 16)));
      float v3 = __half2float(__ushort_as_half((u16)(p3 >> 16)));
      uint3 g0 = *(const uint3*)(Tg + (size_t)c0*384 + loff);
      uint3 g1 = *(const uint3*)(Tg + (size_t)c1*384 + loff);
      uint3 g2 = *(const uint3*)(Tg + (size_t)c2*384 + loff);
      uint3 g3 = *(const uint3*)(Tg + (size_t)c3*384 + loff);
      float vq0 = v0*IPSC, vq1 = v1*IPSC, vq2 = v2*IPSC, vq3 = v3*IPSC;
      FMAXP(g0, v0, vq0); FMAXP(g1, v1, vq1);
      FMAXP(g2, v2, vq2); FMAXP(g3, v3, vq3);
    }
    for (; j < kmax; j += 2) {
      u32 p0 = (u32)__shfl((int)pk, j + half);
      int c0 = p0 & 0xffff; c0 = (c0 < N) ? c0 : 0;
      float v0 = __half2float(__ushort_as_half((u16)(p0 >> 16)));
      uint3 g0 = *(const uint3*)(Tg + (size_t)c0*384 + loff);
      float vq0 = v0*IPSC;
      FMAXP(g0, v0, vq0);
    }
  }
  // combine even/odd-edge partials across halves
  #pragma unroll
  for (int i = 0; i < 4; ++i) {
    ax[i] += __shfl_xor(ax[i], 32);
    ap[i] += __shfl_xor(ap[i], 32);
  }
  // T2 row = [aggx1 (128) | aggx2=aggx1+aggp (128)]; half0 writes x1, half1 x2.
  bf16x4 ob;
  #pragma unroll
  for (int i = 0; i < 4; ++i) {
    float o = half ? (ax[i] + ap[i]) : ax[i];
    ob[i] = (short)f2bf(o);
  }
  *(bf16x4*)(T2 + (size_t)row*256 + half*128 + hl*4) = ob;  // 64 lanes x 8B
}

// K3b: overflow fallback (expected empty) — serial RMW on T2 (raw edges).
__global__ __launch_bounds__(256) void k3b_ovf(
    const int* __restrict__ rowI, const int* __restrict__ colI,
    const float* __restrict__ val, const int* __restrict__ ovfc,
    const int* __restrict__ ovf, const u8* __restrict__ Tg,
    u16* __restrict__ T2)
{
  int n = *ovfc; if (n > 4096) n = 4096;
  for (int i = 0; i < n; ++i) {
    int e = ovf[i];
    int r = rowI[e], c = colI[e];
    float v = val[e];
    int d = threadIdx.x;           // 256 threads cover the 256-wide row
    int dl = d & 127;
    const u8* tgc = Tg + (size_t)c*384 + (dl>>2)*12;
    float xv = bf2f(*(const u16*)(tgc + (dl&3)*2));
    float add = v * xv;
    if (d >= 128) {
      int qb = (int)(signed char)tgc[8 + (dl&3)];
      add = v * (xv + (float)qb * IPSC);
    }
    u16* p = &T2[(size_t)r*256 + d];
    *p = f2bf(bf2f(*p) + add);
  }
}

// K4 (R10 = R8 revert): wave-per-column-slice MFMA with hoisted B-fragments;
// LDS-STAGED wide stores (R9 lesson: per-lane u16 reg-stores caused
// partial-line writeback amplification — WRITE 78->112MB, FETCH +8MB, +15us).
//   passA: cols 128-255 -> Ct=[s1|s3] -> AGGb (16B stores via LDS)
//   passB: cols 0-127 + bias -> Ct=[s0|s2+b] -> embed; stage2 A-operand
//   stage2: P = Ct @ W1 + b1 -> BN partials (per-wave disjoint cols) + Px/Py
__global__ __launch_bounds__(256, 4) void k4_gemm(
    const u16* __restrict__ T2, const u16* __restrict__ Bswz,
    const u16* __restrict__ W1swz,
    const float* __restrict__ b, const float* __restrict__ bt,
    const float* __restrict__ b1, const u8* __restrict__ Tg,
    u16* __restrict__ AGGb, float* __restrict__ outE,
    u16* __restrict__ Px, u16* __restrict__ Py,
    float* __restrict__ partial, int N, int NB)
{
  __shared__ __align__(16) u16 As1[64*STRA];   // 17408B; later red (f32[512])
  __shared__ __align__(16) u16 Ct[64*STRA];    // 17408B half C-tile (u16/bf16)
  const int tid = threadIdx.x;
  const int r0 = blockIdx.x * 32;
  // ---- load A (64 rows: 0-31 = aggx1, 32-63 = aggx2) ----
  #pragma unroll
  for (int i = 0; i < 4; ++i) {
    int f = tid + 256*i;            // 1024 chunks: 64 A-rows x 16 chunks of 8
    int row = f >> 4, c8 = f & 15;
    int r = r0 + (row & 31);
    bf16x8 ch = {0,0,0,0,0,0,0,0};
    if (r < N) ch = *(const bf16x8*)(T2 + (size_t)r*256 + (row>>5)*128 + c8*8);
    *(bf16x8*)&As1[row*STRA + c8*8] = ch;
  }
  __syncthreads();                                        // (1)
  const int w = tid >> 6, l = tid & 63;
  const int m = l & 15, q = l >> 4;
  const int cbase = w*32 + m;        // this wave's column base (+ntl*16)
  f32x4 acc[4][2];
  bf16x8 bfrag[2][4];
  // ---- stage1 pass A: global cols 128..255 ([s1|s3]) ----
  #pragma unroll
  for (int ntl = 0; ntl < 2; ++ntl)
    #pragma unroll
    for (int kt = 0; kt < 4; ++kt)
      bfrag[ntl][kt] = *(const bf16x8*)(Bswz + ((size_t)(kt*16 + 8 + w*2 + ntl)*64 + l)*8);
  #pragma unroll
  for (int rt = 0; rt < 4; ++rt) {
    acc[rt][0] = (f32x4){0.f,0.f,0.f,0.f};
    acc[rt][1] = (f32x4){0.f,0.f,0.f,0.f};
  }
  #pragma unroll
  for (int kt = 0; kt < 4; ++kt)
    #pragma unroll
    for (int rt = 0; rt < 4; ++rt) {
      bf16x8 af = *(const bf16x8*)&As1[(rt*16 + m)*STRA + kt*32 + q*8];
      acc[rt][0] = __builtin_amdgcn_mfma_f32_16x16x32_bf16(af, bfrag[0][kt], acc[rt][0], 0, 0, 0);
      acc[rt][1] = __builtin_amdgcn_mfma_f32_16x16x32_bf16(af, bfrag[1][kt], acc[rt][1], 0, 0, 0);
    }
  #pragma unroll
  for (int ntl = 0; ntl < 2; ++ntl) {
    float bv = bt[cbase + ntl*16];
    #pragma unroll
    for (int rt = 0; rt < 4; ++rt)
      #pragma unroll
      for (int i = 0; i < 4; ++i)
        Ct[(rt*16 + q*4 + i)*STRA + cbase + ntl*16] = f2bf(acc[rt][ntl][i] + bv);
  }
  __syncthreads();                                        // (2)
  // ---- AGGb write: [s1|s3] (rows<32 -> s1 @0, rows>=32 -> s3 @128) ----
  {
    const int ar = tid >> 2, p = tid & 3;
    const int src = r0 + (ar & 31);
    if (src < N) {
      u16* dp = AGGb + (size_t)src*256 + (ar>>5)*128 + p*32;
      const u16* sp = &Ct[ar*STRA + p*32];
      #pragma unroll
      for (int i = 0; i < 4; ++i)
        *(bf16x8*)(dp + i*8) = *(const bf16x8*)(sp + i*8);
    }
  }
  __syncthreads();                                        // (3) Ct reads done
  // ---- stage1 pass B: global cols 0..127 ([s0|s2] + bias) ----
  #pragma unroll
  for (int ntl = 0; ntl < 2; ++ntl)
    #pragma unroll
    for (int kt = 0; kt < 4; ++kt)
      bfrag[ntl][kt] = *(const bf16x8*)(Bswz + ((size_t)(kt*16 + w*2 + ntl)*64 + l)*8);
  #pragma unroll
  for (int rt = 0; rt < 4; ++rt) {
    acc[rt][0] = (f32x4){0.f,0.f,0.f,0.f};
    acc[rt][1] = (f32x4){0.f,0.f,0.f,0.f};
  }
  #pragma unroll
  for (int kt = 0; kt < 4; ++kt)
    #pragma unroll
    for (int rt = 0; rt < 4; ++rt) {
      bf16x8 af = *(const bf16x8*)&As1[(rt*16 + m)*STRA + kt*32 + q*8];
      acc[rt][0] = __builtin_amdgcn_mfma_f32_16x16x32_bf16(af, bfrag[0][kt], acc[rt][0], 0, 0, 0);
      acc[rt][1] = __builtin_amdgcn_mfma_f32_16x16x32_bf16(af, bfrag[1][kt], acc[rt][1], 0, 0, 0);
    }
  #pragma unroll
  for (int ntl = 0; ntl < 2; ++ntl) {
    float bv = b[cbase + ntl*16];
    #pragma unroll
    for (int rt = 0; rt < 4; ++rt)
      #pragma unroll
      for (int i = 0; i < 4; ++i)
        Ct[(rt*16 + q*4 + i)*STRA + cbase + ntl*16] = f2bf(acc[rt][ntl][i] + bv);
  }
  __syncthreads();                                        // (4)
  // ---- embed = x + perb + s2 (Ct rows 32-63, bias incl.); x,perb from Tg ----
  #pragma unroll
  for (int i = 0; i < 2; ++i) {
    int f = tid + 256*i;            // 512 chunks: 32 rows x 16 chunks of 8
    int rr = f >> 4, c8 = f & 15;
    int src = r0 + rr;
    if (src < N) {
      const u16* cp = &Ct[(32+rr)*STRA + c8*8];
      const u8* tg = Tg + (size_t)src*384 + c8*24;   // two 12B chunks
      uint3 ga = *(const uint3*)tg;
      uint3 gb = *(const uint3*)(tg + 12);
      int da = (int)ga.z, db = (int)gb.z;
      float4 e0, e1;
      e0.x = bflo(ga.x) + IPSC*(float)(signed char)(da)     + bf2f(cp[0]);
      e0.y = bfhi(ga.x) + IPSC*(float)(signed char)(da>>8)  + bf2f(cp[1]);
      e0.z = bflo(ga.y) + IPSC*(float)(signed char)(da>>16) + bf2f(cp[2]);
      e0.w = bfhi(ga.y) + IPSC*(float)(da>>24)              + bf2f(cp[3]);
      e1.x = bflo(gb.x) + IPSC*(float)(signed char)(db)     + bf2f(cp[4]);
      e1.y = bfhi(gb.x) + IPSC*(float)(signed char)(db>>8)  + bf2f(cp[5]);
      e1.z = bflo(gb.y) + IPSC*(float)(signed char)(db>>16) + bf2f(cp[6]);
      e1.w = bfhi(gb.y) + IPSC*(float)(db>>24)              + bf2f(cp[7]);
      float* er = outE + (size_t)src*DD + c8*8;
      *(float4*)er = e0;
      *(float4*)(er+4) = e1;
    }
  }
  // ---- stage2 MFMA: P = Ct[:, 0:128] @ W1 (A in-place, stride STRA) ----
  #pragma unroll
  for (int ntl = 0; ntl < 2; ++ntl)
    #pragma unroll
    for (int kt = 0; kt < 4; ++kt)
      bfrag[ntl][kt] = *(const bf16x8*)(W1swz + ((size_t)(kt*8 + w*2 + ntl)*64 + l)*8);
  #pragma unroll
  for (int rt = 0; rt < 4; ++rt) {
    acc[rt][0] = (f32x4){0.f,0.f,0.f,0.f};
    acc[rt][1] = (f32x4){0.f,0.f,0.f,0.f};
  }
  #pragma unroll
  for (int kt = 0; kt < 4; ++kt)
    #pragma unroll
    for (int rt = 0; rt < 4; ++rt) {
      bf16x8 af = *(const bf16x8*)&Ct[(rt*16 + m)*STRA + kt*32 + q*8];
      acc[rt][0] = __builtin_amdgcn_mfma_f32_16x16x32_bf16(af, bfrag[0][kt], acc[rt][0], 0, 0, 0);
      acc[rt][1] = __builtin_amdgcn_mfma_f32_16x16x32_bf16(af, bfrag[1][kt], acc[rt][1], 0, 0, 0);
    }
  // ---- b1 + validity + BN partials (per-wave disjoint cols; red in As1) ----
  float* red = (float*)As1;   // [type(2)][seg(2)][128 cols] = 2KB
  #pragma unroll
  for (int ntl = 0; ntl < 2; ++ntl) {
    float bv = b1[cbase + ntl*16];
    float s0 = 0.f, s1 = 0.f, q0 = 0.f, q1 = 0.f;
    #pragma unroll
    for (int rt = 0; rt < 4; ++rt)
      #pragma unroll
      for (int i = 0; i < 4; ++i) {
        int src = r0 + (((rt*16 + q*4 + i)) & 31);
        float v = (src < N) ? (acc[rt][ntl][i] + bv) : 0.f;
        acc[rt][ntl][i] = v;
        if (rt < 2) { s0 += v; q0 += v*v; } else { s1 += v; q1 += v*v; }
      }
    s0 += __shfl_xor(s0, 16); s0 += __shfl_xor(s0, 32);
    s1 += __shfl_xor(s1, 16); s1 += __shfl_xor(s1, 32);
    q0 += __shfl_xor(q0, 16); q0 += __shfl_xor(q0, 32);
    q1 += __shfl_xor(q1, 16); q1 += __shfl_xor(q1, 32);
    if (l < 16) {
      int c = cbase + ntl*16;     // l<16 => m==l
      red[          c] = s0;
      red[128     + c] = s1;
      red[256     + c] = q0;
      red[256+128 + c] = q1;
    }
  }
  __syncthreads();                                        // (5)
  {
    int type = tid >> 7, col = tid & 127;
    float v0 = red[type*256 + col];          // seg0
    float v1 = red[type*256 + 128 + col];    // seg1
    partial[((size_t)0*NB + blockIdx.x)*256 + tid] = v0;
    partial[((size_t)1*NB + blockIdx.x)*256 + tid] = v1;
  }
  // ---- P-tile (bf16) into Ct: all Ct reads completed before sync(5) ----
  #pragma unroll
  for (int ntl = 0; ntl < 2; ++ntl)
    #pragma unroll
    for (int rt = 0; rt < 4; ++rt)
      #pragma unroll
      for (int i = 0; i < 4; ++i)
        Ct[(rt*16 + q*4 + i)*STRA + cbase + ntl*16] = f2bf(acc[rt][ntl][i]);
  __syncthreads();                                        // (6)
  // ---- P write: rows 0-31 -> Px, rows 32-63 -> Py ----
  {
    const int ar = tid >> 2, p = tid & 3;
    const int src = r0 + (ar & 31);
    if (src < N) {
      const u16* sp = &Ct[ar*STRA + p*32];
      u16* dp = ((ar >> 5) ? Py : Px) + (size_t)src*DD + p*32;
      #pragma unroll
      for (int i = 0; i < 4; ++i)
        *(bf16x8*)(dp + i*8) = *(const bf16x8*)(sp + i*8);
    }
  }
}

// K5b: reduce per-block partials into stats (few atomics).
__global__ __launch_bounds__(256) void k5b_stats(
    const float* __restrict__ partial, float* __restrict__ stats, int nb)
{
  int seg = blockIdx.y, chunk = blockIdx.x, t = threadIdx.x;
  int per = (nb + gridDim.x - 1) / gridDim.x;
  int lo = chunk*per, hi = lo+per; if (hi > nb) hi = nb;
  float s = 0.f;
  const float* p = partial + (size_t)seg*nb*256;
  for (int i = lo; i < hi; ++i) s += p[(size_t)i*256 + t];
  atomicAdd(&stats[seg*256 + t], s);
}

// K6 (kept from R9): BN+PReLU -> MFMA (B hoisted) -> per-wave IN-REGISTER
// cosine partials -> 3KB cross-wave LDS combine -> 1 atomic/block.
// LDS 21.5KB (7 blocks/CU), 3 barriers.
__global__ __launch_bounds__(256) void k6_gemm_loss(
    const u16* __restrict__ Px, const u16* __restrict__ Py,
    const u16* __restrict__ AGGb, const float* __restrict__ stats,
    const float* __restrict__ gamma, const float* __restrict__ beta,
    const float* __restrict__ aP, const u16* __restrict__ W2swz,
    const float* __restrict__ b2, float* __restrict__ gloss, int N)
{
  __shared__ __align__(16) u16 As[64*STRA];      // 17408B
  __shared__ float s1s[128], s2s[128];
  __shared__ float redp[4][64], redt[4][64], redx[4][64];   // 3KB
  const int tid = threadIdx.x;
  const int seg = blockIdx.y;
  const u16* __restrict__ P = seg ? Py : Px;
  const int toff = seg ? 0 : 128;
  const float invN = 1.f / (float)N;
  if (tid < 128) {
    float mu = stats[seg*256 + tid] * invN;
    float var = stats[seg*256 + 128 + tid] * invN - mu*mu;
    float rstd = rsqrtf(var + 1e-5f);
    float s1 = rstd * gamma[tid];
    s1s[tid] = s1;
    s2s[tid] = beta[tid] - mu*s1;
  }
  const float alpha = aP[0];
  const int r0 = blockIdx.x * 64;
  __syncthreads();                                        // (a)
  #pragma unroll
  for (int i = 0; i < 4; ++i) {
    int f = tid + 256*i;
    int row = f >> 4, c8 = f & 15;
    int r = r0 + row;
    bf16x8 ch = {0,0,0,0,0,0,0,0};
    if (r < N) ch = *(const bf16x8*)(P + (size_t)r*DD + c8*8);
    bf16x8 a;
    #pragma unroll
    for (int t2 = 0; t2 < 8; ++t2) {
      int colc = c8*8 + t2;
      float hv = bf2f((u16)ch[t2]);
      float hn = hv*s1s[colc] + s2s[colc];
      hn = hn >= 0.f ? hn : alpha*hn;
      a[t2] = (short)f2bf(hn);
    }
    *(bf16x8*)&As[row*STRA + c8*8] = a;
  }
  __syncthreads();                                        // (b)
  const int w = tid >> 6, l = tid & 63;
  const int m = l & 15, q = l >> 4;
  const int cbase = w*32 + m;
  f32x4 acc[4][2];
  bf16x8 bfrag[2][4];
  #pragma unroll
  for (int ntl = 0; ntl < 2; ++ntl)
    #pragma unroll
    for (int kt = 0; kt < 4; ++kt)
      bfrag[ntl][kt] = *(const bf16x8*)(W2swz + ((size_t)(kt*8 + w*2 + ntl)*64 + l)*8);
  #pragma unroll
  for (int rt = 0; rt < 4; ++rt) {
    acc[rt][0] = (f32x4){0.f,0.f,0.f,0.f};
    acc[rt][1] = (f32x4){0.f,0.f,0.f,0.f};
  }
  #pragma unroll
  for (int kt = 0; kt < 4; ++kt)
    #pragma unroll
    for (int rt = 0; rt < 4; ++rt) {
      bf16x8 af = *(const bf16x8*)&As[(rt*16 + m)*STRA + kt*32 + q*8];
      acc[rt][0] = __builtin_amdgcn_mfma_f32_16x16x32_bf16(af, bfrag[0][kt], acc[rt][0], 0, 0, 0);
      acc[rt][1] = __builtin_amdgcn_mfma_f32_16x16x32_bf16(af, bfrag[1][kt], acc[rt][1], 0, 0, 0);
    }
  // ---- per-wave cosine partials over this wave's 32 cols ----
  const float b20 = b2[cbase], b21 = b2[cbase + 16];
  #pragma unroll
  for (int rt = 0; rt < 4; ++rt)
    #pragma unroll
    for (int i = 0; i < 4; ++i) {
      int row = rt*16 + q*4 + i;
      int r = r0 + row;
      float p0 = 0.f, p1 = 0.f, t0 = 0.f, t1 = 0.f;
      if (r < N) {
        p0 = acc[rt][0][i] + b20;
        p1 = acc[rt][1][i] + b21;
        t0 = bf2f(AGGb[(size_t)r*256 + toff + cbase]);
        t1 = bf2f(AGGb[(size_t)r*256 + toff + cbase + 16]);
      }
      float pp = p0*p0 + p1*p1;
      float tt = t0*t0 + t1*t1;
      float pt = p0*t0 + p1*t1;
      pp += __shfl_xor(pp, 1); pp += __shfl_xor(pp, 2);
      pp += __shfl_xor(pp, 4); pp += __shfl_xor(pp, 8);
      tt += __shfl_xor(tt, 1); tt += __shfl_xor(tt, 2);
      tt += __shfl_xor(tt, 4); tt += __shfl_xor(tt, 8);
      pt += __shfl_xor(pt, 1); pt += __shfl_xor(pt, 2);
      pt += __shfl_xor(pt, 4); pt += __shfl_xor(pt, 8);
      if (m == 0) { redp[w][row] = pp; redt[w][row] = tt; redx[w][row] = pt; }
    }
  __syncthreads();                                        // (c)
  if (tid < 64) {
    int r = r0 + tid;
    float pp = redp[0][tid] + redp[1][tid] + redp[2][tid] + redp[3][tid];
    float tt = redt[0][tid] + redt[1][tid] + redt[2][tid] + redt[3][tid];
    float pt = redx[0][tid] + redx[1][tid] + redx[2][tid] + redx[3][tid];
    float ls = 0.f;
    if (r < N) ls = 2.f - 2.f * pt * rsqrtf(pp * tt);
    ls += __shfl_xor(ls, 1);  ls += __shfl_xor(ls, 2);
    ls += __shfl_xor(ls, 4);  ls += __shfl_xor(ls, 8);
    ls += __shfl_xor(ls, 16); ls += __shfl_xor(ls, 32);
    if (tid == 0) atomicAdd(gloss, ls);
  }
}

__global__ void k7_loss(const float* __restrict__ gloss, float* __restrict__ out, int N, int total)
{
  out[total] = gloss[0] / (float)N;
}

extern "C" void kernel_launch(void* const* d_in, const int* in_sizes, int n_in,
                              void* d_out, int out_size, void* d_ws, size_t ws_size,
                              hipStream_t stream)
{
  const float* x    = (const float*)d_in[0];
  const float* perb = (const float*)d_in[1];
  const int*   erow = (const int*)d_in[2];
  const int*   ecol = (const int*)d_in[3];
  const float* eval_= (const float*)d_in[4];
  const float* W    = (const float*)d_in[5];
  const float* b    = (const float*)d_in[6];
  const float* Wt   = (const float*)d_in[7];
  const float* bt   = (const float*)d_in[8];
  const float* W1   = (const float*)d_in[9];
  const float* b1   = (const float*)d_in[10];
  const float* gam  = (const float*)d_in[11];
  const float* bet  = (const float*)d_in[12];
  const float* aP   = (const float*)d_in[13];
  const float* W2   = (const float*)d_in[14];
  const float* b2   = (const float*)d_in[15];
  const int N = in_sizes[0] / DD;
  const int E = in_sizes[2];
  const int NB4 = (N + 31)/32;
  const int NB5 = (N + 63)/64;
  const int rowsPerPart = (N + NPART - 1) / NPART;

  char* ws = (char*)d_ws;
  size_t off = 0;
  auto alloc = [&](size_t bytes) -> void* {
    void* p = ws + off;
    off += (bytes + 255) & ~(size_t)255;
    return p;
  };
  u16*   AGGb = (u16*)  alloc((size_t)N*256*sizeof(u16));   // 25.6 MB [s1|s3]
  u8*    Tg   = (u8*)   alloc((size_t)N*384);               // 19.2 MB gather table
  u16*   T2   = (u16*)  alloc((size_t)N*256*sizeof(u16));   // 25.6 MB
  u16*   Px   = (u16*)  alloc((size_t)N*DD*sizeof(u16));    // 12.8 MB
  u16*   Py   = (u16*)  alloc((size_t)N*DD*sizeof(u16));    // 12.8 MB
  int*   deg  = (int*)  alloc((size_t)N*sizeof(int));
  float* stats= (float*)alloc(512*sizeof(float));
  float* gloss= (float*)alloc(256);
  int*   ovfc = (int*)((char*)gloss + 64);
  u32*   perm = (u32*)  alloc((size_t)N*CAP*sizeof(u32));   // 12.8 MB packed
  int*   ovf  = (int*)  alloc(4096*sizeof(int));
  u16*   Bswz = (u16*)  alloc(32768*sizeof(u16));
  u16*   W1swz= (u16*)  alloc(16384*sizeof(u16));
  u16*   W2swz= (u16*)  alloc(16384*sizeof(u16));
  float* partial = (float*)alloc((size_t)2*NB4*256*sizeof(float)); // 3.2 MB
  if (ws_size < off) return;

  kU_init<<<(N*32 + 255)/256, 256, 0, stream>>>(x, perb, W, Wt, W1, W2,
                                                Tg, Bswz, W1swz, W2swz,
                                                deg, stats, gloss, N);
  k2_bucket<<<2048, 256, 0, stream>>>(erow, ecol, eval_, E, deg, perm, ovfc, ovf,
                                      rowsPerPart);
  k3_spmm<<<(N + 3)/4, 256, 0, stream>>>(perm, deg, Tg, T2, N);
  k3b_ovf<<<1, 256, 0, stream>>>(erow, ecol, eval_, ovfc, ovf, Tg, T2);
  k4_gemm<<<NB4, 256, 0, stream>>>(T2, Bswz, W1swz, b, bt, b1, Tg,
                                   AGGb, (float*)d_out, Px, Py, partial, N, NB4);
  k5b_stats<<<dim3(16, 2), 256, 0, stream>>>(partial, stats, NB4);
  k6_gemm_loss<<<dim3(NB5, 2), 256, 0, stream>>>(Px, Py, AGGb, stats, gam, bet, aP,
                                                 W2swz, b2, gloss, N);
  k7_loss<<<1, 1, 0, stream>>>(gloss, (float*)d_out, N, N*DD);
}